// Round 7
// baseline (403.316 us; speedup 1.0000x reference)
//
#include <hip/hip_runtime.h>
#include <math.h>

#define IN_DIM 16
#define HIDN 128
#define NH 8
#define DHD 16
#define NTYPE 12
#define NLAYERS 4
#define NPG 5000
#define NSEGP 250
#define RPS (NPG / NSEGP)   // rows per pool segment = 20
#define C1 656
#define C2 1312
#define CAP 128
#define NPW 4               // nodes (waves) per k_edge block

__device__ __forceinline__ float gelu_t(float x) {
    float x3 = x * x * x;
    float u = 0.7978845608028654f * (x + 0.044715f * x3);
    return 0.5f * x * (1.0f + tanhf(u));
}

__device__ __forceinline__ unsigned pack_bf16(float lo, float hi) {
    unsigned a = __float_as_uint(lo);
    unsigned b = __float_as_uint(hi);
    a = (a + 0x7fffu + ((a >> 16) & 1u)) >> 16;
    b = (b + 0x7fffu + ((b >> 16) & 1u)) & 0xffff0000u;
    return a | b;
}

__device__ __forceinline__ float lrelu(float x) { return (x >= 0.f) ? x : 0.2f * x; }

// ---- init: ea table + zero cursors ----
__global__ __launch_bounds__(256) void k_init(const float* __restrict__ etab,
                                              const float* __restrict__ aed,
                                              float* __restrict__ ea, int* __restrict__ c1,
                                              int* __restrict__ c2, int N) {
    int i = blockIdx.x * 256 + threadIdx.x;
    if (i < NTYPE * NH) {
        int t = i / NH, hh = i % NH;
        float s = 0.f;
        #pragma unroll
        for (int d = 0; d < DHD; d++) s += etab[t * HIDN + hh * DHD + d] * aed[hh * DHD + d];
        ea[i] = s;
    }
    if (i < N) {
        c1[i] = 0;
        c2[i] = 0;
    }
}

// ---- embed: h = gelu(feat_masked @ We + be); write feat + h0 to out ----
__global__ __launch_bounds__(128) void k_embed(const float* __restrict__ feat,
                                               const float* __restrict__ We,
                                               const float* __restrict__ be,
                                               float* __restrict__ h, float* __restrict__ out,
                                               int N) {
    int n = blockIdx.x;
    int c = threadIdx.x;
    __shared__ float f[IN_DIM];
    if (c < IN_DIM) {
        float v = feat[n * IN_DIM + c];
        if ((c >= 2 && c < 4) || c >= 10) v = 0.f;
        f[c] = v;
        out[(size_t)n * C2 + c] = v;
    }
    __syncthreads();
    float a = be[c];
    #pragma unroll
    for (int k = 0; k < IN_DIM; k++) a += f[k] * We[k * HIDN + c];
    float g = gelu_t(a);
    h[(size_t)n * HIDN + c] = g;
    out[(size_t)n * C2 + IN_DIM + c] = g;
}

// ---- CSR build ----
__global__ void k_count(const int* __restrict__ dstp, int* __restrict__ cnt, int E) {
    int e = blockIdx.x * 256 + threadIdx.x;
    if (e < E) atomicAdd(&cnt[dstp[e]], 1);
}

#define SCANT 1024
__global__ __launch_bounds__(SCANT) void k_scan(const int* __restrict__ cnt,
                                                int* __restrict__ rowptr, int N) {
    __shared__ int sums[SCANT];
    int t = threadIdx.x;
    int per = (N + SCANT - 1) / SCANT;
    int lo = t * per, hi = lo + per;
    if (hi > N) hi = N;
    int s = 0;
    for (int i = lo; i < hi; i++) s += cnt[i];
    sums[t] = s;
    __syncthreads();
    for (int off = 1; off < SCANT; off <<= 1) {
        int v = (t >= off) ? sums[t - off] : 0;
        __syncthreads();
        sums[t] += v;
        __syncthreads();
    }
    int run = (t == 0) ? 0 : sums[t - 1];
    for (int i = lo; i < hi; i++) {
        rowptr[i] = run;
        run += cnt[i];
    }
    if (t == SCANT - 1) rowptr[N] = run;
}

__global__ void k_scatter(const int* __restrict__ srcp, const int* __restrict__ dstp,
                          const int* __restrict__ etp, const int* __restrict__ rowptr,
                          int* __restrict__ cursor, unsigned* __restrict__ payload, int E) {
    int e = blockIdx.x * 256 + threadIdx.x;
    if (e < E) {
        int d = dstp[e];
        int pos = rowptr[d] + atomicAdd(&cursor[d], 1);
        payload[pos] = (unsigned)srcp[e] | ((unsigned)etp[e] << 16);
    }
}

// ---- per-layer GEMM: 32-row tiles for occupancy; fused logits; bf16-packed z ----
#define KC 64
__global__ __launch_bounds__(256) void k_gemm(const float* __restrict__ h,
                                              const float* __restrict__ W,
                                              const float* __restrict__ asf,
                                              const float* __restrict__ adf,
                                              unsigned* __restrict__ z16,
                                              float* __restrict__ slog,
                                              float* __restrict__ dlog, int N) {
    __shared__ float Wc[KC][HIDN];
    __shared__ float hc[32][KC + 4];
    int t = threadIdx.x;
    int cg = t & 15, rg = t >> 4;   // 16 col-groups x 16 row-groups(2 rows each)
    int n0 = blockIdx.x * 32;
    int c0 = cg * 8;
    float acc[2][8];
    #pragma unroll
    for (int i = 0; i < 2; i++)
        #pragma unroll
        for (int j = 0; j < 8; j++) acc[i][j] = 0.f;

    for (int k0 = 0; k0 < HIDN; k0 += KC) {
        for (int i = t; i < KC * 32; i += 256) {
            int kk = i >> 5, cc = (i & 31) << 2;
            *(float4*)&Wc[kk][cc] = *(const float4*)&W[(k0 + kk) * HIDN + cc];
        }
        for (int i = t; i < 32 * (KC / 4); i += 256) {
            int rr = i / (KC / 4), kk = (i % (KC / 4)) * 4;
            int n = n0 + rr;
            float4 v = make_float4(0.f, 0.f, 0.f, 0.f);
            if (n < N) v = *(const float4*)&h[(size_t)n * HIDN + k0 + kk];
            *(float4*)&hc[rr][kk] = v;
        }
        __syncthreads();
        for (int k = 0; k < KC; k++) {
            float4 w0 = *(float4*)&Wc[k][c0];
            float4 w1 = *(float4*)&Wc[k][c0 + 4];
            float hv[2];
            #pragma unroll
            for (int i = 0; i < 2; i++) hv[i] = hc[rg * 2 + i][k];
            #pragma unroll
            for (int i = 0; i < 2; i++) {
                acc[i][0] += hv[i] * w0.x;
                acc[i][1] += hv[i] * w0.y;
                acc[i][2] += hv[i] * w0.z;
                acc[i][3] += hv[i] * w0.w;
                acc[i][4] += hv[i] * w1.x;
                acc[i][5] += hv[i] * w1.y;
                acc[i][6] += hv[i] * w1.z;
                acc[i][7] += hv[i] * w1.w;
            }
        }
        __syncthreads();
    }
    float4 s0 = *(const float4*)&asf[c0];
    float4 s1 = *(const float4*)&asf[c0 + 4];
    float4 d0 = *(const float4*)&adf[c0];
    float4 d1 = *(const float4*)&adf[c0 + 4];
    #pragma unroll
    for (int i = 0; i < 2; i++) {
        int n = n0 + rg * 2 + i;
        float ps = acc[i][0] * s0.x + acc[i][1] * s0.y + acc[i][2] * s0.z + acc[i][3] * s0.w +
                   acc[i][4] * s1.x + acc[i][5] * s1.y + acc[i][6] * s1.z + acc[i][7] * s1.w;
        float pd = acc[i][0] * d0.x + acc[i][1] * d0.y + acc[i][2] * d0.z + acc[i][3] * d0.w +
                   acc[i][4] * d1.x + acc[i][5] * d1.y + acc[i][6] * d1.z + acc[i][7] * d1.w;
        ps += __shfl_xor(ps, 1);
        pd += __shfl_xor(pd, 1);
        unsigned u[8];
        #pragma unroll
        for (int j = 0; j < 8; j++) {
            float other = __shfl_xor(acc[i][j], 8);
            u[j] = pack_bf16(acc[i][j], other);
        }
        if (n < N) {
            if (cg < 8) {
                uint4 v0 = make_uint4(u[0], u[1], u[2], u[3]);
                uint4 v1 = make_uint4(u[4], u[5], u[6], u[7]);
                *(uint4*)&z16[(size_t)n * 64 + c0] = v0;
                *(uint4*)&z16[(size_t)n * 64 + c0 + 4] = v1;
            }
            if ((cg & 1) == 0) {
                slog[n * NH + (cg >> 1)] = ps;
                dlog[n * NH + (cg >> 1)] = pd;
            }
        }
    }
}

// ---- per-layer edge aggregation: one wave per dst node, register logits ----
__global__ __launch_bounds__(256) void k_edge(const int* __restrict__ rowptr,
                                              const unsigned* __restrict__ payload,
                                              const float* __restrict__ slog,
                                              const float* __restrict__ dlog,
                                              const float* __restrict__ ea,
                                              const unsigned* __restrict__ z16,
                                              float* __restrict__ h,
                                              float* __restrict__ out, int colbase, int N) {
    int wave = threadIdx.x >> 6, lane = threadIdx.x & 63;
    int n = blockIdx.x * NPW + wave;
    bool active = (n < N);
    __shared__ float lbuf[NPW][CAP * NH];
    __shared__ unsigned pbuf[NPW][CAP];
    __shared__ float sea[NTYPE * NH];

    if (threadIdx.x < NTYPE * NH) sea[threadIdx.x] = ea[threadIdx.x];

    int rs = 0, cnt = 0;
    float4 dla = make_float4(0.f, 0.f, 0.f, 0.f), dlb = dla;
    if (active) {
        rs = rowptr[n];
        int re = rowptr[n + 1];
        cnt = re - rs;
        if (cnt > CAP) cnt = CAP;
        dla = *(const float4*)&dlog[n * NH];
        dlb = *(const float4*)&dlog[n * NH + 4];
    }
    for (int e = lane; e < cnt; e += 64) pbuf[wave][e] = payload[rs + e];
    __syncthreads();   // pbuf + sea ready

    // logits: lane = edge, all 8 heads in registers (2 rounds cover CAP=128)
    float lg[2][8];
    #pragma unroll
    for (int r = 0; r < 2; r++)
        #pragma unroll
        for (int j = 0; j < 8; j++) lg[r][j] = -3.4e38f;
    #pragma unroll
    for (int r = 0; r < 2; r++) {
        int el = lane + r * 64;
        if (el < cnt) {
            unsigned pk = pbuf[wave][el];
            int src = pk & 0xffff;
            int et = pk >> 16;
            float4 sa = *(const float4*)&slog[src * NH];
            float4 sb = *(const float4*)&slog[src * NH + 4];
            float4 e4a = *(float4*)&sea[et * NH];
            float4 e4b = *(float4*)&sea[et * NH + 4];
            lg[r][0] = lrelu(sa.x + dla.x + e4a.x);
            lg[r][1] = lrelu(sa.y + dla.y + e4a.y);
            lg[r][2] = lrelu(sa.z + dla.z + e4a.z);
            lg[r][3] = lrelu(sa.w + dla.w + e4a.w);
            lg[r][4] = lrelu(sb.x + dlb.x + e4b.x);
            lg[r][5] = lrelu(sb.y + dlb.y + e4b.y);
            lg[r][6] = lrelu(sb.z + dlb.z + e4b.z);
            lg[r][7] = lrelu(sb.w + dlb.w + e4b.w);
        }
    }
    // per-head max across the wave
    float m8[8];
    #pragma unroll
    for (int j = 0; j < 8; j++) m8[j] = fmaxf(lg[0][j], lg[1][j]);
    #pragma unroll
    for (int m = 1; m < 64; m <<= 1)
        #pragma unroll
        for (int j = 0; j < 8; j++) m8[j] = fmaxf(m8[j], __shfl_xor(m8[j], m));
    // exp from registers, store alpha-weights, per-head sum
    float s8[8];
    #pragma unroll
    for (int j = 0; j < 8; j++) s8[j] = 0.f;
    #pragma unroll
    for (int r = 0; r < 2; r++) {
        int el = lane + r * 64;
        if (el < cnt) {
            float4 xa, xb;
            xa.x = expf(lg[r][0] - m8[0]);
            xa.y = expf(lg[r][1] - m8[1]);
            xa.z = expf(lg[r][2] - m8[2]);
            xa.w = expf(lg[r][3] - m8[3]);
            xb.x = expf(lg[r][4] - m8[4]);
            xb.y = expf(lg[r][5] - m8[5]);
            xb.z = expf(lg[r][6] - m8[6]);
            xb.w = expf(lg[r][7] - m8[7]);
            *(float4*)&lbuf[wave][el * NH] = xa;
            *(float4*)&lbuf[wave][el * NH + 4] = xb;
            s8[0] += xa.x; s8[1] += xa.y; s8[2] += xa.z; s8[3] += xa.w;
            s8[4] += xb.x; s8[5] += xb.y; s8[6] += xb.z; s8[7] += xb.w;
        }
    }
    #pragma unroll
    for (int m = 1; m < 64; m <<= 1)
        #pragma unroll
        for (int j = 0; j < 8; j++) s8[j] += __shfl_xor(s8[j], m);

    // each lane picks its two head denominators (h1 = lane>>4, h2 = h1+4)
    int h1 = lane >> 4, h2 = h1 + 4;
    float d1 = (lane < 16) ? s8[0] : (lane < 32) ? s8[1] : (lane < 48) ? s8[2] : s8[3];
    float d2 = (lane < 16) ? s8[4] : (lane < 32) ? s8[5] : (lane < 48) ? s8[6] : s8[7];
    float r1 = 1.0f / (d1 + 1e-9f);
    float r2 = 1.0f / (d2 + 1e-9f);

    // aggregation: lane owns cols (lane, lane+64) packed in one u32 per src row
    float a0 = 0.f, a1 = 0.f;
    int e = 0;
    for (; e + 7 < cnt; e += 8) {
        unsigned v[8];
        #pragma unroll
        for (int j = 0; j < 8; j++) {
            unsigned s = pbuf[wave][e + j] & 0xffff;
            v[j] = z16[(size_t)s * 64 + lane];
        }
        #pragma unroll
        for (int j = 0; j < 8; j++) {
            float l0 = lbuf[wave][(e + j) * NH + h1];
            float l1 = lbuf[wave][(e + j) * NH + h2];
            a0 += l0 * __uint_as_float(v[j] << 16);
            a1 += l1 * __uint_as_float(v[j] & 0xffff0000u);
        }
    }
    for (; e < cnt; e++) {
        unsigned s0 = pbuf[wave][e] & 0xffff;
        unsigned v0 = z16[(size_t)s0 * 64 + lane];
        a0 += lbuf[wave][e * NH + h1] * __uint_as_float(v0 << 16);
        a1 += lbuf[wave][e * NH + h2] * __uint_as_float(v0 & 0xffff0000u);
    }
    if (active) {
        a0 *= r1;
        a1 *= r2;
        size_t hb = (size_t)n * HIDN;
        float o0 = h[hb + lane] + gelu_t(a0);
        float o1 = h[hb + lane + 64] + gelu_t(a1);
        h[hb + lane] = o0;
        h[hb + lane + 64] = o1;
        size_t ob = (size_t)n * C2 + colbase;
        out[ob + lane] = o0;
        out[ob + lane + 64] = o1;
    }
}

// ---- graph max-pool ----
__global__ __launch_bounds__(256) void k_pool_partial(const float* __restrict__ out,
                                                      float* __restrict__ gpart) {
    int b = blockIdx.x / NSEGP, seg = blockIdx.x % NSEGP;
    int n0 = b * NPG + seg * RPS;
    for (int c = threadIdx.x; c < C1; c += 256) {
        float m = -3.4e38f;
        #pragma unroll
        for (int i = 0; i < RPS; i++) m = fmaxf(m, out[(size_t)(n0 + i) * C2 + c]);
        gpart[(size_t)(b * NSEGP + seg) * C1 + c] = m;
    }
}

__global__ void k_pool_final(const float* __restrict__ gpart, float* __restrict__ gemb, int B) {
    int j = blockIdx.x * 256 + threadIdx.x;
    if (j < B * C1) {
        int b = j / C1, c = j % C1;
        float m = -3.4e38f;
        for (int s = 0; s < NSEGP; s++) m = fmaxf(m, gpart[(size_t)(b * NSEGP + s) * C1 + c]);
        gemb[j] = m;
    }
}

#define C1Q (C1 / 4)   // 164 float4 per row
__global__ __launch_bounds__(256) void k_bcast(const float* __restrict__ gemb,
                                               float* __restrict__ out, int N) {
    int idx = blockIdx.x * 256 + threadIdx.x;
    if (idx < N * C1Q) {
        int n = idx / C1Q, c4 = idx % C1Q;
        int b = n / NPG;
        float4 g = *(const float4*)&gemb[b * C1 + c4 * 4];
        *(float4*)&out[(size_t)n * C2 + C1 + c4 * 4] = g;
    }
}

extern "C" void kernel_launch(void* const* d_in, const int* in_sizes, int n_in, void* d_out,
                              int out_size, void* d_ws, size_t ws_size, hipStream_t stream) {
    const float* feat = (const float*)d_in[0];
    const float* etab = (const float*)d_in[1];
    const float* We = (const float*)d_in[2];
    const float* be = (const float*)d_in[3];
    const float* Wc = (const float*)d_in[4];
    const float* a_src = (const float*)d_in[5];
    const float* a_dst = (const float*)d_in[6];
    const float* a_edge = (const float*)d_in[7];
    const int* eidx = (const int*)d_in[8];
    const int* etype = (const int*)d_in[9];
    float* out = (float*)d_out;

    const int N = in_sizes[0] / IN_DIM;   // 20000
    const int E = in_sizes[9];            // 660000
    const int B = N / NPG;                // 4

    const int* srcp = eidx;
    const int* dstp = eidx + E;

    char* w = (char*)d_ws;
    size_t off = 0;
    auto carve = [&](size_t bytes) {
        char* p = w + off;
        off = (off + bytes + 255) & ~(size_t)255;
        return p;
    };
    float* h = (float*)carve((size_t)N * HIDN * 4);
    unsigned* z16 = (unsigned*)carve((size_t)N * 64 * 4);
    float* slog = (float*)carve((size_t)N * NH * 4);
    float* dlog = (float*)carve((size_t)N * NH * 4);
    float* ea = (float*)carve(NTYPE * NH * 4);
    int* rowptr = (int*)carve((size_t)(N + 1) * 4);
    int* cursor = (int*)carve((size_t)N * 4);
    int* cursor2 = (int*)carve((size_t)N * 4);
    unsigned* payload = (unsigned*)carve((size_t)E * 4);
    float* gpart = (float*)carve((size_t)B * NSEGP * C1 * 4);
    float* gemb = (float*)carve((size_t)B * C1 * 4);
    (void)ws_size;

    k_init<<<(N + 255) / 256, 256, 0, stream>>>(etab, a_edge, ea, cursor, cursor2, N);
    k_embed<<<N, 128, 0, stream>>>(feat, We, be, h, out, N);

    k_count<<<(E + 255) / 256, 256, 0, stream>>>(dstp, cursor, E);
    k_scan<<<1, SCANT, 0, stream>>>(cursor, rowptr, N);
    k_scatter<<<(E + 255) / 256, 256, 0, stream>>>(srcp, dstp, etype, rowptr, cursor2, payload, E);

    for (int l = 0; l < NLAYERS; l++) {
        k_gemm<<<(N + 31) / 32, 256, 0, stream>>>(h, Wc, a_src, a_dst, z16, slog, dlog, N);
        int colbase = IN_DIM + HIDN * (l + 1);
        k_edge<<<(N + NPW - 1) / NPW, 256, 0, stream>>>(rowptr, payload, slog, dlog, ea, z16, h,
                                                        out, colbase, N);
    }

    k_pool_partial<<<B * NSEGP, 256, 0, stream>>>(out, gpart);
    k_pool_final<<<(B * C1 + 255) / 256, 256, 0, stream>>>(gpart, gemb, B);
    k_bcast<<<((size_t)N * C1Q + 255) / 256, 256, 0, stream>>>(gemb, out, N);
}

// Round 8
// 372.899 us; speedup vs baseline: 1.0816x; 1.0816x over previous
//
#include <hip/hip_runtime.h>
#include <math.h>

#define IN_DIM 16
#define HIDN 128
#define NH 8
#define DHD 16
#define NTYPE 12
#define NLAYERS 4
#define NPG 5000
#define NSEGP 250
#define RPS (NPG / NSEGP)   // rows per pool segment = 20
#define C1 656
#define C2 1312
#define CAP 128
#define NPW 4               // nodes (waves) per k_edge block
#define HREG (NPG / 2)      // 2500 rows per (graph,half) region
#define GEMM_SLOTS ((HREG + 63) / 64)   // 40
#define EDGE_SLOTS (HREG / NPW)          // 625

__device__ __forceinline__ float gelu_t(float x) {
    float x3 = x * x * x;
    float u = 0.7978845608028654f * (x + 0.044715f * x3);
    return 0.5f * x * (1.0f + tanhf(u));
}

__device__ __forceinline__ unsigned pack_bf16(float lo, float hi) {
    unsigned a = __float_as_uint(lo);
    unsigned b = __float_as_uint(hi);
    a = (a + 0x7fffu + ((a >> 16) & 1u)) >> 16;
    b = (b + 0x7fffu + ((b >> 16) & 1u)) & 0xffff0000u;
    return a | b;
}

__device__ __forceinline__ float lrelu(float x) { return (x >= 0.f) ? x : 0.2f * x; }

// ---- init: ea table + zero cursors ----
__global__ __launch_bounds__(256) void k_init(const float* __restrict__ etab,
                                              const float* __restrict__ aed,
                                              float* __restrict__ ea, int* __restrict__ c1,
                                              int* __restrict__ c2, int N) {
    int i = blockIdx.x * 256 + threadIdx.x;
    if (i < NTYPE * NH) {
        int t = i / NH, hh = i % NH;
        float s = 0.f;
        #pragma unroll
        for (int d = 0; d < DHD; d++) s += etab[t * HIDN + hh * DHD + d] * aed[hh * DHD + d];
        ea[i] = s;
    }
    if (i < N) {
        c1[i] = 0;
        c2[i] = 0;
    }
}

// ---- embed: h = gelu(feat_masked @ We + be); write feat + h0 to out ----
__global__ __launch_bounds__(128) void k_embed(const float* __restrict__ feat,
                                               const float* __restrict__ We,
                                               const float* __restrict__ be,
                                               float* __restrict__ h, float* __restrict__ out,
                                               int N) {
    int n = blockIdx.x;
    int c = threadIdx.x;
    __shared__ float f[IN_DIM];
    if (c < IN_DIM) {
        float v = feat[n * IN_DIM + c];
        if ((c >= 2 && c < 4) || c >= 10) v = 0.f;
        f[c] = v;
        out[(size_t)n * C2 + c] = v;
    }
    __syncthreads();
    float a = be[c];
    #pragma unroll
    for (int k = 0; k < IN_DIM; k++) a += f[k] * We[k * HIDN + c];
    float g = gelu_t(a);
    h[(size_t)n * HIDN + c] = g;
    out[(size_t)n * C2 + IN_DIM + c] = g;
}

// ---- CSR build ----
__global__ void k_count(const int* __restrict__ dstp, int* __restrict__ cnt, int E) {
    int e = blockIdx.x * 256 + threadIdx.x;
    if (e < E) atomicAdd(&cnt[dstp[e]], 1);
}

#define SCANT 1024
__global__ __launch_bounds__(SCANT) void k_scan(const int* __restrict__ cnt,
                                                int* __restrict__ rowptr, int N) {
    __shared__ int sums[SCANT];
    int t = threadIdx.x;
    int per = (N + SCANT - 1) / SCANT;
    int lo = t * per, hi = lo + per;
    if (hi > N) hi = N;
    int s = 0;
    for (int i = lo; i < hi; i++) s += cnt[i];
    sums[t] = s;
    __syncthreads();
    for (int off = 1; off < SCANT; off <<= 1) {
        int v = (t >= off) ? sums[t - off] : 0;
        __syncthreads();
        sums[t] += v;
        __syncthreads();
    }
    int run = (t == 0) ? 0 : sums[t - 1];
    for (int i = lo; i < hi; i++) {
        rowptr[i] = run;
        run += cnt[i];
    }
    if (t == SCANT - 1) rowptr[N] = run;
}

__global__ void k_scatter(const int* __restrict__ srcp, const int* __restrict__ dstp,
                          const int* __restrict__ etp, const int* __restrict__ rowptr,
                          int* __restrict__ cursor, unsigned* __restrict__ payload, int E) {
    int e = blockIdx.x * 256 + threadIdx.x;
    if (e < E) {
        int d = dstp[e];
        int pos = rowptr[d] + atomicAdd(&cursor[d], 1);
        payload[pos] = (unsigned)srcp[e] | ((unsigned)etp[e] << 16);
    }
}

// ---- per-layer GEMM: 64-row tiles, XCD-region mapped; fused logits; bf16 z ----
// blockIdx%8 = XCD (HW round-robin). graph g -> XCDs {g, g+4}; each XCD owns
// a 2500-row half-region so z16/slog rows are produced in the consumer's L2.
#define KC 64
__global__ __launch_bounds__(256) void k_gemm(const float* __restrict__ h,
                                              const float* __restrict__ W,
                                              const float* __restrict__ asf,
                                              const float* __restrict__ adf,
                                              unsigned* __restrict__ z16,
                                              float* __restrict__ slog,
                                              float* __restrict__ dlog, int N) {
    __shared__ float Wc[KC][HIDN];
    __shared__ float hc[64][KC + 4];
    int xcd = blockIdx.x & 7, slot = blockIdx.x >> 3;
    int g = xcd & 3, half = xcd >> 2;
    int base = g * NPG + half * HREG;
    int rend = base + HREG;
    int n0 = base + slot * 64;
    int t = threadIdx.x;
    int cg = t & 15, rg = t >> 4;
    int c0 = cg * 8;
    float acc[4][8];
    #pragma unroll
    for (int i = 0; i < 4; i++)
        #pragma unroll
        for (int j = 0; j < 8; j++) acc[i][j] = 0.f;

    for (int k0 = 0; k0 < HIDN; k0 += KC) {
        for (int i = t; i < KC * 32; i += 256) {
            int kk = i >> 5, cc = (i & 31) << 2;
            *(float4*)&Wc[kk][cc] = *(const float4*)&W[(k0 + kk) * HIDN + cc];
        }
        for (int i = t; i < 64 * (KC / 4); i += 256) {
            int rr = i / (KC / 4), kk = (i % (KC / 4)) * 4;
            int n = n0 + rr;
            float4 v = make_float4(0.f, 0.f, 0.f, 0.f);
            if (n < rend) v = *(const float4*)&h[(size_t)n * HIDN + k0 + kk];
            *(float4*)&hc[rr][kk] = v;
        }
        __syncthreads();
        for (int k = 0; k < KC; k++) {
            float4 w0 = *(float4*)&Wc[k][c0];
            float4 w1 = *(float4*)&Wc[k][c0 + 4];
            float hv[4];
            #pragma unroll
            for (int i = 0; i < 4; i++) hv[i] = hc[rg * 4 + i][k];
            #pragma unroll
            for (int i = 0; i < 4; i++) {
                acc[i][0] += hv[i] * w0.x;
                acc[i][1] += hv[i] * w0.y;
                acc[i][2] += hv[i] * w0.z;
                acc[i][3] += hv[i] * w0.w;
                acc[i][4] += hv[i] * w1.x;
                acc[i][5] += hv[i] * w1.y;
                acc[i][6] += hv[i] * w1.z;
                acc[i][7] += hv[i] * w1.w;
            }
        }
        __syncthreads();
    }
    float4 s0 = *(const float4*)&asf[c0];
    float4 s1 = *(const float4*)&asf[c0 + 4];
    float4 d0 = *(const float4*)&adf[c0];
    float4 d1 = *(const float4*)&adf[c0 + 4];
    #pragma unroll
    for (int i = 0; i < 4; i++) {
        int n = n0 + rg * 4 + i;
        float ps = acc[i][0] * s0.x + acc[i][1] * s0.y + acc[i][2] * s0.z + acc[i][3] * s0.w +
                   acc[i][4] * s1.x + acc[i][5] * s1.y + acc[i][6] * s1.z + acc[i][7] * s1.w;
        float pd = acc[i][0] * d0.x + acc[i][1] * d0.y + acc[i][2] * d0.z + acc[i][3] * d0.w +
                   acc[i][4] * d1.x + acc[i][5] * d1.y + acc[i][6] * d1.z + acc[i][7] * d1.w;
        ps += __shfl_xor(ps, 1);
        pd += __shfl_xor(pd, 1);
        unsigned u[8];
        #pragma unroll
        for (int j = 0; j < 8; j++) {
            float other = __shfl_xor(acc[i][j], 8);
            u[j] = pack_bf16(acc[i][j], other);
        }
        if (n < rend) {
            if (cg < 8) {
                uint4 v0 = make_uint4(u[0], u[1], u[2], u[3]);
                uint4 v1 = make_uint4(u[4], u[5], u[6], u[7]);
                *(uint4*)&z16[(size_t)n * 64 + c0] = v0;
                *(uint4*)&z16[(size_t)n * 64 + c0 + 4] = v1;
            }
            if ((cg & 1) == 0) {
                slog[n * NH + (cg >> 1)] = ps;
                dlog[n * NH + (cg >> 1)] = pd;
            }
        }
    }
}

// ---- per-layer edge aggregation: one wave per dst node, XCD-region mapped ----
__global__ __launch_bounds__(256) void k_edge(const int* __restrict__ rowptr,
                                              const unsigned* __restrict__ payload,
                                              const float* __restrict__ slog,
                                              const float* __restrict__ dlog,
                                              const float* __restrict__ ea,
                                              const unsigned* __restrict__ z16,
                                              float* __restrict__ h,
                                              float* __restrict__ out, int colbase, int N) {
    int wave = threadIdx.x >> 6, lane = threadIdx.x & 63;
    int xcd = blockIdx.x & 7, slot = blockIdx.x >> 3;
    int g = xcd & 3, half = xcd >> 2;
    int unit = g * (NPG / NPW) + half * EDGE_SLOTS + slot;
    int n = unit * NPW + wave;
    bool active = (n < N);
    __shared__ float lbuf[NPW][CAP * NH];
    __shared__ unsigned pbuf[NPW][CAP];
    __shared__ float dl[NPW][NH];
    __shared__ float red[NPW][NH];
    __shared__ float sea[NTYPE * NH];

    if (threadIdx.x < NTYPE * NH) sea[threadIdx.x] = ea[threadIdx.x];

    int rs = 0, cnt = 0;
    if (active) {
        rs = rowptr[n];
        int re = rowptr[n + 1];
        cnt = re - rs;
        if (cnt > CAP) cnt = CAP;
        if (lane < NH) dl[wave][lane] = dlog[n * NH + lane];
    }
    for (int e = lane; e < cnt; e += 64) pbuf[wave][e] = payload[rs + e];
    __syncthreads();

    // logits: float4 lanes, 2 lanes/edge, 32 edges per round; leaky fused
    int o = lane & 1;          // half: heads 4o..4o+3
    int eoff = lane >> 1;
    float4 dl4 = *(float4*)&dl[wave][o * 4];
    float4 rmax4 = make_float4(-3.4e38f, -3.4e38f, -3.4e38f, -3.4e38f);
    for (int base = 0; base < cnt; base += 32) {
        int el = base + eoff;
        if (el < cnt) {
            unsigned pk = pbuf[wave][el];
            int src = pk & 0xffff;
            int et = pk >> 16;
            float4 s4 = *(const float4*)&slog[src * NH + o * 4];
            float4 e4 = *(float4*)&sea[et * NH + o * 4];
            float4 lg;
            lg.x = lrelu(s4.x + dl4.x + e4.x);
            lg.y = lrelu(s4.y + dl4.y + e4.y);
            lg.z = lrelu(s4.z + dl4.z + e4.z);
            lg.w = lrelu(s4.w + dl4.w + e4.w);
            *(float4*)&lbuf[wave][el * NH + o * 4] = lg;
            rmax4.x = fmaxf(rmax4.x, lg.x);
            rmax4.y = fmaxf(rmax4.y, lg.y);
            rmax4.z = fmaxf(rmax4.z, lg.z);
            rmax4.w = fmaxf(rmax4.w, lg.w);
        }
    }
    #pragma unroll
    for (int m = 2; m <= 32; m <<= 1) {
        rmax4.x = fmaxf(rmax4.x, __shfl_xor(rmax4.x, m));
        rmax4.y = fmaxf(rmax4.y, __shfl_xor(rmax4.y, m));
        rmax4.z = fmaxf(rmax4.z, __shfl_xor(rmax4.z, m));
        rmax4.w = fmaxf(rmax4.w, __shfl_xor(rmax4.w, m));
    }
    float4 ssum4 = make_float4(0.f, 0.f, 0.f, 0.f);
    for (int base = 0; base < cnt; base += 32) {
        int el = base + eoff;
        if (el < cnt) {
            float4 l4 = *(float4*)&lbuf[wave][el * NH + o * 4];
            l4.x = expf(l4.x - rmax4.x);
            l4.y = expf(l4.y - rmax4.y);
            l4.z = expf(l4.z - rmax4.z);
            l4.w = expf(l4.w - rmax4.w);
            *(float4*)&lbuf[wave][el * NH + o * 4] = l4;
            ssum4.x += l4.x;
            ssum4.y += l4.y;
            ssum4.z += l4.z;
            ssum4.w += l4.w;
        }
    }
    #pragma unroll
    for (int m = 2; m <= 32; m <<= 1) {
        ssum4.x += __shfl_xor(ssum4.x, m);
        ssum4.y += __shfl_xor(ssum4.y, m);
        ssum4.z += __shfl_xor(ssum4.z, m);
        ssum4.w += __shfl_xor(ssum4.w, m);
    }
    if (lane < 2) {
        float4 r4;
        r4.x = 1.0f / (ssum4.x + 1e-9f);
        r4.y = 1.0f / (ssum4.y + 1e-9f);
        r4.z = 1.0f / (ssum4.z + 1e-9f);
        r4.w = 1.0f / (ssum4.w + 1e-9f);
        *(float4*)&red[wave][o * 4] = r4;
    }
    __syncthreads();

    // aggregation: lane owns cols (lane, lane+64) packed in one u32 per src row
    int h1 = lane >> 4, h2 = h1 + 4;
    float r1 = red[wave][h1], r2 = red[wave][h2];
    float a0 = 0.f, a1 = 0.f;
    int e = 0;
    for (; e + 7 < cnt; e += 8) {
        unsigned v[8];
        #pragma unroll
        for (int j = 0; j < 8; j++) {
            unsigned s = pbuf[wave][e + j] & 0xffff;
            v[j] = z16[(size_t)s * 64 + lane];
        }
        #pragma unroll
        for (int j = 0; j < 8; j++) {
            float l0 = lbuf[wave][(e + j) * NH + h1];
            float l1 = lbuf[wave][(e + j) * NH + h2];
            a0 += l0 * __uint_as_float(v[j] << 16);
            a1 += l1 * __uint_as_float(v[j] & 0xffff0000u);
        }
    }
    for (; e < cnt; e++) {
        unsigned s0 = pbuf[wave][e] & 0xffff;
        unsigned v0 = z16[(size_t)s0 * 64 + lane];
        a0 += lbuf[wave][e * NH + h1] * __uint_as_float(v0 << 16);
        a1 += lbuf[wave][e * NH + h2] * __uint_as_float(v0 & 0xffff0000u);
    }
    if (active) {
        a0 *= r1;
        a1 *= r2;
        size_t hb = (size_t)n * HIDN;
        float o0 = h[hb + lane] + gelu_t(a0);
        float o1 = h[hb + lane + 64] + gelu_t(a1);
        h[hb + lane] = o0;
        h[hb + lane + 64] = o1;
        size_t ob = (size_t)n * C2 + colbase;
        out[ob + lane] = o0;
        out[ob + lane + 64] = o1;
    }
}

// ---- graph max-pool ----
__global__ __launch_bounds__(256) void k_pool_partial(const float* __restrict__ out,
                                                      float* __restrict__ gpart) {
    int b = blockIdx.x / NSEGP, seg = blockIdx.x % NSEGP;
    int n0 = b * NPG + seg * RPS;
    for (int c = threadIdx.x; c < C1; c += 256) {
        float m = -3.4e38f;
        #pragma unroll
        for (int i = 0; i < RPS; i++) m = fmaxf(m, out[(size_t)(n0 + i) * C2 + c]);
        gpart[(size_t)(b * NSEGP + seg) * C1 + c] = m;
    }
}

__global__ void k_pool_final(const float* __restrict__ gpart, float* __restrict__ gemb, int B) {
    int j = blockIdx.x * 256 + threadIdx.x;
    if (j < B * C1) {
        int b = j / C1, c = j % C1;
        float m = -3.4e38f;
        for (int s = 0; s < NSEGP; s++) m = fmaxf(m, gpart[(size_t)(b * NSEGP + s) * C1 + c]);
        gemb[j] = m;
    }
}

#define C1Q (C1 / 4)   // 164 float4 per row
__global__ __launch_bounds__(256) void k_bcast(const float* __restrict__ gemb,
                                               float* __restrict__ out, int N) {
    int idx = blockIdx.x * 256 + threadIdx.x;
    if (idx < N * C1Q) {
        int n = idx / C1Q, c4 = idx % C1Q;
        int b = n / NPG;
        float4 g = *(const float4*)&gemb[b * C1 + c4 * 4];
        *(float4*)&out[(size_t)n * C2 + C1 + c4 * 4] = g;
    }
}

extern "C" void kernel_launch(void* const* d_in, const int* in_sizes, int n_in, void* d_out,
                              int out_size, void* d_ws, size_t ws_size, hipStream_t stream) {
    const float* feat = (const float*)d_in[0];
    const float* etab = (const float*)d_in[1];
    const float* We = (const float*)d_in[2];
    const float* be = (const float*)d_in[3];
    const float* Wc = (const float*)d_in[4];
    const float* a_src = (const float*)d_in[5];
    const float* a_dst = (const float*)d_in[6];
    const float* a_edge = (const float*)d_in[7];
    const int* eidx = (const int*)d_in[8];
    const int* etype = (const int*)d_in[9];
    float* out = (float*)d_out;

    const int N = in_sizes[0] / IN_DIM;   // 20000
    const int E = in_sizes[9];            // 660000
    const int B = N / NPG;                // 4

    const int* srcp = eidx;
    const int* dstp = eidx + E;

    char* w = (char*)d_ws;
    size_t off = 0;
    auto carve = [&](size_t bytes) {
        char* p = w + off;
        off = (off + bytes + 255) & ~(size_t)255;
        return p;
    };
    float* h = (float*)carve((size_t)N * HIDN * 4);
    unsigned* z16 = (unsigned*)carve((size_t)N * 64 * 4);
    float* slog = (float*)carve((size_t)N * NH * 4);
    float* dlog = (float*)carve((size_t)N * NH * 4);
    float* ea = (float*)carve(NTYPE * NH * 4);
    int* rowptr = (int*)carve((size_t)(N + 1) * 4);
    int* cursor = (int*)carve((size_t)N * 4);
    int* cursor2 = (int*)carve((size_t)N * 4);
    unsigned* payload = (unsigned*)carve((size_t)E * 4);
    float* gpart = (float*)carve((size_t)B * NSEGP * C1 * 4);
    float* gemb = (float*)carve((size_t)B * C1 * 4);
    (void)ws_size;

    k_init<<<(N + 255) / 256, 256, 0, stream>>>(etab, a_edge, ea, cursor, cursor2, N);
    k_embed<<<N, 128, 0, stream>>>(feat, We, be, h, out, N);

    k_count<<<(E + 255) / 256, 256, 0, stream>>>(dstp, cursor, E);
    k_scan<<<1, SCANT, 0, stream>>>(cursor, rowptr, N);
    k_scatter<<<(E + 255) / 256, 256, 0, stream>>>(srcp, dstp, etype, rowptr, cursor2, payload, E);

    for (int l = 0; l < NLAYERS; l++) {
        k_gemm<<<8 * GEMM_SLOTS, 256, 0, stream>>>(h, Wc, a_src, a_dst, z16, slog, dlog, N);
        int colbase = IN_DIM + HIDN * (l + 1);
        k_edge<<<8 * ((NPG / NPW / 2)) , 256, 0, stream>>>(rowptr, payload, slog, dlog, ea, z16,
                                                           h, out, colbase, N);
    }

    k_pool_partial<<<B * NSEGP, 256, 0, stream>>>(out, gpart);
    k_pool_final<<<(B * C1 + 255) / 256, 256, 0, stream>>>(gpart, gemb, B);
    k_bcast<<<((size_t)N * C1Q + 255) / 256, 256, 0, stream>>>(gemb, out, N);
}